// Round 2
// baseline (2419.756 us; speedup 1.0000x reference)
//
#include <hip/hip_runtime.h>
#include <hip/hip_bf16.h>

// Mamba2 fused block, MI355X. Round 2: compact-workspace (126.5 MiB) bf16
// intermediates, f32 accumulation. Runtime f32/bf16 input detection (ws flag).
//
// Dims: B=2 L=4096 DM=1024 DIN=2048 H=32 P=64 N=128 CHUNK=256 NC=16
// DPROJ=4384 CONVD=2304

#define LL 4096
#define DPROJ 4384
#define CONVD 2304
#define DIN 2048
#define NH 32
#define HD 64
#define DS 128
#define CH 256
#define NC 16

typedef unsigned short u16;
typedef unsigned int u32;

__device__ __forceinline__ float bf2f(u16 v) {
    u32 x = ((u32)v) << 16;
    float f; __builtin_memcpy(&f, &x, 4); return f;
}
__device__ __forceinline__ u16 f2bf(float f) {
    u32 x; __builtin_memcpy(&x, &f, 4);
    u32 r = (x + 0x7fffu + ((x >> 16) & 1u)) >> 16;   // RNE
    return (u16)r;
}
__device__ __forceinline__ float ldin(const void* p, size_t i, int bf) {
    if (bf) return bf2f(((const u16*)p)[i]);
    return ((const float*)p)[i];
}
__device__ __forceinline__ void stout(void* p, size_t i, int bf, float v) {
    if (bf) ((u16*)p)[i] = f2bf(v);
    else    ((float*)p)[i] = v;
}

// ---------------- dtype detector ----------------
// bf16 input: u16[2t] are bf16 values with N(0,1)-plausible exponents.
// f32 input: u16[2t] are low mantissa halves, exponent field ~uniform.
__global__ void k_detect(const void* u, int* flag) {
    __shared__ int cnt;
    if (threadIdx.x == 0) cnt = 0;
    __syncthreads();
    u16 bits = ((const u16*)u)[2 * threadIdx.x];
    int e = (bits >> 7) & 0xff;
    int ok = (e >= 100 && e <= 141) ? 1 : 0;
    atomicAdd(&cnt, ok);
    __syncthreads();
    if (threadIdx.x == 0) *flag = (cnt > 128) ? 1 : 0;
}

// ---------------- GEMM1: [8192,1024] @ [1024,4384] -> split Zb/XBCr/DTraw ----------------
__global__ __launch_bounds__(256) void k_gemm1(const void* A, const void* Bm,
                                               u16* Zb, u16* XBCr, u16* DTraw,
                                               const int* flagp) {
    int fl = *flagp;
    __shared__ float As[16][68];
    __shared__ float Bs[16][68];
    int t = threadIdx.x;
    int tx = t & 15, ty = t >> 4;
    int m0 = blockIdx.y * 64, n0 = blockIdx.x * 64;
    float acc[4][4];
#pragma unroll
    for (int i = 0; i < 4; ++i)
#pragma unroll
        for (int j = 0; j < 4; ++j) acc[i][j] = 0.f;

    for (int k0 = 0; k0 < 1024; k0 += 16) {
        for (int i = t; i < 1024; i += 256) {
            int m = i >> 4, k = i & 15;
            As[k][m] = ldin(A, (size_t)(m0 + m) * 1024 + k0 + k, fl);
        }
        for (int i = t; i < 1024; i += 256) {
            int k = i >> 6, n = i & 63;
            float v = 0.f;
            if (n0 + n < DPROJ) v = ldin(Bm, (size_t)(k0 + k) * DPROJ + n0 + n, fl);
            Bs[k][n] = v;
        }
        __syncthreads();
#pragma unroll
        for (int k = 0; k < 16; ++k) {
            float4 a4 = *(const float4*)&As[k][ty * 4];
            float4 b4 = *(const float4*)&Bs[k][tx * 4];
            float av[4] = {a4.x, a4.y, a4.z, a4.w};
            float bv[4] = {b4.x, b4.y, b4.z, b4.w};
#pragma unroll
            for (int i = 0; i < 4; ++i)
#pragma unroll
                for (int j = 0; j < 4; ++j) acc[i][j] += av[i] * bv[j];
        }
        __syncthreads();
    }
#pragma unroll
    for (int i = 0; i < 4; ++i) {
        size_t m = m0 + ty * 4 + i;
#pragma unroll
        for (int j = 0; j < 4; ++j) {
            int n = n0 + tx * 4 + j;
            float v = acc[i][j];
            if (n < DIN) Zb[m * DIN + n] = f2bf(v);
            else if (n < 2 * DIN + 2 * DS) XBCr[m * CONVD + (n - DIN)] = f2bf(v);
            else if (n < DPROJ) DTraw[m * NH + (n - 2 * DIN - 2 * DS)] = f2bf(v);
        }
    }
}

// ---------------- dt softplus + per-chunk cumsum of dA ----------------
__global__ __launch_bounds__(256) void k_dtcum(const u16* DTraw, const void* dtb, const void* alog,
                                               const int* flagp, float* DT, float* ACS, float* AL) {
    int fl = *flagp;
    int bid = blockIdx.x;                 // (b*16+c)*32+h
    int b = bid >> 9, c = (bid >> 5) & 15, h = bid & 31;
    int t = threadIdx.x;
    size_t bl = (size_t)b * LL + c * CH + t;
    float v = bf2f(DTraw[bl * NH + h]) + ldin(dtb, h, fl);
    float sp = (v > 20.f) ? v : log1pf(__expf(v));
    DT[bl * NH + h] = sp;
    float da = -__expf(ldin(alog, h, fl)) * sp;
    __shared__ float sc[256];
    sc[t] = da;
    __syncthreads();
    for (int off = 1; off < 256; off <<= 1) {
        float add = (t >= off) ? sc[t - off] : 0.f;
        __syncthreads();
        sc[t] += add;
        __syncthreads();
    }
    ACS[(size_t)bid * CH + t] = sc[t];
    if (t == 255) AL[bid] = sc[255];
}

// ---------------- causal depthwise conv (width 4) + silu ----------------
__global__ void k_conv(const u16* XBCr, const void* cw, const void* cb, const int* flagp, u16* XCb) {
    int fl = *flagp;
    int ch = blockIdx.x * 256 + threadIdx.x;   // 0..2303 (grid.x = 9)
    size_t bl = blockIdx.y;                    // 0..8191
    int l = (int)(bl & 4095);
    float acc = ldin(cb, ch, fl);
#pragma unroll
    for (int j = 0; j < 4; ++j) {
        int ls = l + j - 3;
        if (ls >= 0)
            acc += bf2f(XBCr[(bl - l + ls) * CONVD + ch]) * ldin(cw, (size_t)ch * 4 + j, fl);
    }
    acc = acc / (1.f + __expf(-acc));
    XCb[bl * CONVD + ch] = f2bf(acc);
}

// ---------------- scores G[l,s] = C[l].B[s] per (b,c) ----------------
__global__ __launch_bounds__(256) void k_scores(const u16* XCb, u16* G) {
    int z = blockIdx.z;   // b*16+c
    const u16* base = XCb + (size_t)z * CH * CONVD;
    __shared__ float As[16][68];
    __shared__ float Bs[16][68];
    int t = threadIdx.x;
    int tx = t & 15, ty = t >> 4;
    int m0 = blockIdx.y * 64, n0 = blockIdx.x * 64;
    float acc[4][4];
#pragma unroll
    for (int i = 0; i < 4; ++i)
#pragma unroll
        for (int j = 0; j < 4; ++j) acc[i][j] = 0.f;

    for (int k0 = 0; k0 < DS; k0 += 16) {
        for (int i = t; i < 1024; i += 256) {
            int m = i >> 4, k = i & 15;
            As[k][m] = bf2f(base[(size_t)(m0 + m) * CONVD + (DIN + DS) + k0 + k]);
        }
        for (int i = t; i < 1024; i += 256) {
            int n = i >> 4, k = i & 15;
            Bs[k][n] = bf2f(base[(size_t)(n0 + n) * CONVD + DIN + k0 + k]);
        }
        __syncthreads();
#pragma unroll
        for (int k = 0; k < 16; ++k) {
            float4 a4 = *(const float4*)&As[k][ty * 4];
            float4 b4 = *(const float4*)&Bs[k][tx * 4];
            float av[4] = {a4.x, a4.y, a4.z, a4.w};
            float bv[4] = {b4.x, b4.y, b4.z, b4.w};
#pragma unroll
            for (int i = 0; i < 4; ++i)
#pragma unroll
                for (int j = 0; j < 4; ++j) acc[i][j] += av[i] * bv[j];
        }
        __syncthreads();
    }
    size_t gb = (size_t)z * 65536;
#pragma unroll
    for (int i = 0; i < 4; ++i) {
        int m = m0 + ty * 4 + i;
#pragma unroll
        for (int j = 0; j < 4; ++j) {
            int n = n0 + tx * 4 + j;
            G[gb + (size_t)m * CH + n] = f2bf(acc[i][j]);
        }
    }
}

// ---------------- per-chunk states[n][p] = sum_l B[l,n]*exp(Alast-Acs[l])*X[l,p]*dt[l] ----------------
__global__ __launch_bounds__(256) void k_states(const u16* XCb, const float* DT, const float* ACS,
                                                const float* AL, u16* ST) {
    int bid = blockIdx.x;
    int b = bid >> 9, c = (bid >> 5) & 15, h = bid & 31;
    int t = threadIdx.x;
    size_t bL = (size_t)b * LL + c * CH;
    __shared__ float Xt[32 * 68];
    __shared__ float Bt[32 * 132];
    float al = AL[bid];
    const float* acs = ACS + (size_t)bid * CH;
    float acc[8][4];
#pragma unroll
    for (int j = 0; j < 8; ++j)
#pragma unroll
        for (int i = 0; i < 4; ++i) acc[j][i] = 0.f;
    int p0 = (t & 15) * 4;
    int n0 = (t >> 4) * 8;
    for (int lt = 0; lt < 8; ++lt) {
        int l0 = lt * 32;
        __syncthreads();
        for (int i = t; i < 2048; i += 256) {
            int j = i >> 6, p = i & 63;
            int l = l0 + j;
            float w = __expf(al - acs[l]) * DT[(bL + l) * NH + h];
            Xt[j * 68 + p] = bf2f(XCb[(bL + l) * CONVD + h * HD + p]) * w;
        }
        for (int i = t; i < 4096; i += 256) {
            int j = i >> 7, n = i & 127;
            Bt[j * 132 + n] = bf2f(XCb[(bL + l0 + j) * CONVD + DIN + n]);
        }
        __syncthreads();
#pragma unroll
        for (int l = 0; l < 32; ++l) {
            float4 xv = *(const float4*)&Xt[l * 68 + p0];
            float4 b0 = *(const float4*)&Bt[l * 132 + n0];
            float4 b1 = *(const float4*)&Bt[l * 132 + n0 + 4];
            float bj[8] = {b0.x, b0.y, b0.z, b0.w, b1.x, b1.y, b1.z, b1.w};
            float xi[4] = {xv.x, xv.y, xv.z, xv.w};
#pragma unroll
            for (int j = 0; j < 8; ++j)
#pragma unroll
                for (int i = 0; i < 4; ++i) acc[j][i] += bj[j] * xi[i];
        }
    }
    size_t sbase = (size_t)bid * 8192;
#pragma unroll
    for (int j = 0; j < 8; ++j)
#pragma unroll
        for (int i = 0; i < 4; ++i)
            ST[sbase + (size_t)(n0 + j) * 64 + p0 + i] = f2bf(acc[j][i]);
}

// ---------------- inter-chunk scan (in place; f32 carry in registers) ----------------
__global__ __launch_bounds__(256) void k_scan(const float* AL, u16* ST) {
    int bid = blockIdx.x;  // b*32+h
    int b = bid >> 5, h = bid & 31;
    int t = threadIdx.x;
    float Pv[32];
#pragma unroll
    for (int k = 0; k < 32; ++k) Pv[k] = 0.f;
    for (int c = 0; c < NC; ++c) {
        int bch = (b * NC + c) * NH + h;
        float ga = __expf(AL[bch]);
        size_t base = (size_t)bch * 8192;
#pragma unroll
        for (int k = 0; k < 32; ++k) {
            size_t idx = base + (size_t)k * 256 + t;
            float s = bf2f(ST[idx]);
            ST[idx] = f2bf(Pv[k]);
            Pv[k] = ga * Pv[k] + s;
        }
    }
}

// ---------------- Y = Y_off + Y_diag, per (b,c,h); thread t owns row l=t ----------------
__global__ __launch_bounds__(256) void k_ydiag(const u16* XCb, const float* DT, const float* ACS,
                                               const u16* G, const u16* ST, u16* Yb) {
    int bid = blockIdx.x;
    int b = bid >> 9, c = (bid >> 5) & 15, h = bid & 31;
    int t = threadIdx.x;
    size_t bL = (size_t)b * LL + c * CH;
    size_t gbase = (size_t)(b * NC + c) * 65536;
    size_t pbase = (size_t)bid * 8192;
    __shared__ float acs_s[256];
    __shared__ char smem[52224];
    float* Pl = (float*)smem;            // 128 x 68
    float* Ct = (float*)(smem + 34816);  // 256 x 17
    float* Gt = (float*)smem;            // 256 x 33 (phase B)
    float* Xt = (float*)(smem + 33792);  // 32 x 68  (phase B)

    acs_s[t] = ACS[(size_t)bid * CH + t];
    for (int i = t; i < 8192; i += 256)
        Pl[(i >> 6) * 68 + (i & 63)] = bf2f(ST[pbase + i]);  // [n][p]
    __syncthreads();
    float myA = acs_s[t];
    float accp[64];
#pragma unroll
    for (int i = 0; i < 64; ++i) accp[i] = 0.f;

    // phase A: Y_off = exp(Acs[l]) * sum_n C[l,n] * P[n,p]
    for (int nt = 0; nt < 8; ++nt) {
        __syncthreads();
        for (int i = t; i < 4096; i += 256) {
            int row = i >> 4, col = i & 15;
            Ct[row * 17 + col] = bf2f(XCb[(bL + row) * CONVD + DIN + DS + nt * 16 + col]);
        }
        __syncthreads();
#pragma unroll
        for (int j = 0; j < 16; ++j) {
            float cf = Ct[t * 17 + j];
            const float4* pr = (const float4*)&Pl[(nt * 16 + j) * 68];
#pragma unroll
            for (int q = 0; q < 16; ++q) {
                float4 pv = pr[q];
                accp[q * 4 + 0] += cf * pv.x; accp[q * 4 + 1] += cf * pv.y;
                accp[q * 4 + 2] += cf * pv.z; accp[q * 4 + 3] += cf * pv.w;
            }
        }
    }
    float od = __expf(myA);
#pragma unroll
    for (int i = 0; i < 64; ++i) accp[i] *= od;

    // phase B: Y_diag = sum_{s<=l} G[l,s]*exp(Acs[l]-Acs[s]) * X[s,p]*dt[s]
    for (int st8 = 0; st8 < 8; ++st8) {
        int s0 = st8 * 32;
        __syncthreads();
        for (int i = t; i < 8192; i += 256) {
            int row = i >> 5, col = i & 31;
            Gt[row * 33 + col] = bf2f(G[gbase + (size_t)row * 256 + s0 + col]);
        }
        for (int i = t; i < 2048; i += 256) {
            int j = i >> 6, p = i & 63;
            int s = s0 + j;
            Xt[j * 68 + p] = bf2f(XCb[(bL + s) * CONVD + h * HD + p]) * DT[(bL + s) * NH + h];
        }
        __syncthreads();
        if (t >= s0) {
            int jmax = t - s0; if (jmax > 31) jmax = 31;
            for (int j = 0; j <= jmax; ++j) {
                float cf = Gt[t * 33 + j] * __expf(myA - acs_s[s0 + j]);
                const float4* xr = (const float4*)&Xt[j * 68];
#pragma unroll
                for (int q = 0; q < 16; ++q) {
                    float4 xv = xr[q];
                    accp[q * 4 + 0] += cf * xv.x; accp[q * 4 + 1] += cf * xv.y;
                    accp[q * 4 + 2] += cf * xv.z; accp[q * 4 + 3] += cf * xv.w;
                }
            }
        }
    }
    size_t ybase = (bL + t) * (size_t)DIN + h * HD;
    u32* yo = (u32*)&Yb[ybase];
#pragma unroll
    for (int q = 0; q < 32; ++q)
        yo[q] = (u32)f2bf(accp[2 * q]) | ((u32)f2bf(accp[2 * q + 1]) << 16);
}

// ---------------- layernorm over 2048 * norm_w * silu(z), in place on Yb ----------------
__global__ __launch_bounds__(256) void k_norm(u16* Yb, const u16* Zb, const void* nw, const int* flagp) {
    int fl = *flagp;
    size_t row = blockIdx.x;
    int t = threadIdx.x;
    size_t base = row * (size_t)DIN;
    float v[8];
#pragma unroll
    for (int k = 0; k < 8; ++k) v[k] = bf2f(Yb[base + k * 256 + t]);
    float s = 0.f;
#pragma unroll
    for (int k = 0; k < 8; ++k) s += v[k];
#pragma unroll
    for (int off = 32; off > 0; off >>= 1) s += __shfl_down(s, off);
    __shared__ float red[4];
    int wid = t >> 6, lid = t & 63;
    if (lid == 0) red[wid] = s;
    __syncthreads();
    float mu = (red[0] + red[1] + red[2] + red[3]) * (1.f / 2048.f);
    float d = 0.f;
#pragma unroll
    for (int k = 0; k < 8; ++k) { float e = v[k] - mu; d += e * e; }
#pragma unroll
    for (int off = 32; off > 0; off >>= 1) d += __shfl_down(d, off);
    __syncthreads();
    if (lid == 0) red[wid] = d;
    __syncthreads();
    float var = (red[0] + red[1] + red[2] + red[3]) * (1.f / 2048.f);
    float rs = rsqrtf(var + 1e-5f);
#pragma unroll
    for (int k = 0; k < 8; ++k) {
        int dcol = k * 256 + t;
        float z = bf2f(Zb[row * DIN + dcol]);
        float sz = z / (1.f + __expf(-z));
        Yb[base + dcol] = f2bf((v[k] - mu) * rs * ldin(nw, dcol, fl) * sz);
    }
}

// ---------------- GEMM2: out = Yb[8192,2048] @ Wout[2048,1024] ----------------
__global__ __launch_bounds__(256) void k_gemm2(const u16* Yb, const void* Bm, void* C,
                                               const int* flagp) {
    int fl = *flagp;
    __shared__ float As[16][68];
    __shared__ float Bs[16][68];
    int t = threadIdx.x;
    int tx = t & 15, ty = t >> 4;
    int m0 = blockIdx.y * 64, n0 = blockIdx.x * 64;
    float acc[4][4];
#pragma unroll
    for (int i = 0; i < 4; ++i)
#pragma unroll
        for (int j = 0; j < 4; ++j) acc[i][j] = 0.f;

    for (int k0 = 0; k0 < DIN; k0 += 16) {
        for (int i = t; i < 1024; i += 256) {
            int m = i >> 4, k = i & 15;
            As[k][m] = bf2f(Yb[(size_t)(m0 + m) * DIN + k0 + k]);
        }
        for (int i = t; i < 1024; i += 256) {
            int k = i >> 6, n = i & 63;
            Bs[k][n] = ldin(Bm, (size_t)(k0 + k) * 1024 + n0 + n, fl);
        }
        __syncthreads();
#pragma unroll
        for (int k = 0; k < 16; ++k) {
            float4 a4 = *(const float4*)&As[k][ty * 4];
            float4 b4 = *(const float4*)&Bs[k][tx * 4];
            float av[4] = {a4.x, a4.y, a4.z, a4.w};
            float bv[4] = {b4.x, b4.y, b4.z, b4.w};
#pragma unroll
            for (int i = 0; i < 4; ++i)
#pragma unroll
                for (int j = 0; j < 4; ++j) acc[i][j] += av[i] * bv[j];
        }
        __syncthreads();
    }
#pragma unroll
    for (int i = 0; i < 4; ++i) {
        size_t m = m0 + ty * 4 + i;
#pragma unroll
        for (int j = 0; j < 4; ++j) {
            int n = n0 + tx * 4 + j;
            stout(C, m * 1024 + n, fl, acc[i][j]);
        }
    }
}

extern "C" void kernel_launch(void* const* d_in, const int* in_sizes, int n_in,
                              void* d_out, int out_size, void* d_ws, size_t ws_size,
                              hipStream_t stream) {
    const void* u    = d_in[0];
    const void* Win  = d_in[1];
    const void* cw   = d_in[2];
    const void* cb   = d_in[3];
    const void* dtb  = d_in[4];
    const void* alog = d_in[5];
    const void* nw   = d_in[6];
    const void* Wout = d_in[7];

    char* base = (char*)d_ws;
    int*  flag  = (int*)base;
    u16*  Zb    = (u16*)(base + 256);               // 33,554,432 B
    u16*  XBCr  = (u16*)(base + 33554688);          // 37,748,736 B (Yb aliases)
    u16*  XCb   = (u16*)(base + 71303424);          // 37,748,736 B
    u16*  ST    = (u16*)(base + 109052160);         // 16,777,216 B
    u16*  G     = (u16*)(base + 125829376);         //  4,194,304 B
    float* DT   = (float*)(base + 130023680);       //  1,048,576 B
    float* ACS  = (float*)(base + 131072256);       //  1,048,576 B
    float* AL   = (float*)(base + 132120832);       //      4,096 B
    u16*  DTraw = (u16*)(base + 132124928);         //    524,288 B  (end 132,649,216)
    u16*  Yb    = XBCr;                             // alias: XBCr dead after conv

    k_detect<<<1, 256, 0, stream>>>(u, flag);
    k_gemm1<<<dim3(69, 128), 256, 0, stream>>>(u, Win, Zb, XBCr, DTraw, flag);
    k_dtcum<<<1024, 256, 0, stream>>>(DTraw, dtb, alog, flag, DT, ACS, AL);
    k_conv<<<dim3(9, 8192), 256, 0, stream>>>(XBCr, cw, cb, flag, XCb);
    k_scores<<<dim3(4, 4, 32), 256, 0, stream>>>(XCb, G);
    k_states<<<1024, 256, 0, stream>>>(XCb, DT, ACS, AL, ST);
    k_scan<<<64, 256, 0, stream>>>(AL, ST);
    k_ydiag<<<1024, 256, 0, stream>>>(XCb, DT, ACS, G, ST, Yb);
    k_norm<<<8192, 256, 0, stream>>>(Yb, Zb, nw, flag);
    k_gemm2<<<dim3(16, 128), 256, 0, stream>>>(Yb, Wout, d_out, flag);
}

// Round 3
// 889.240 us; speedup vs baseline: 2.7211x; 2.7211x over previous
//
#include <hip/hip_runtime.h>
#include <hip/hip_bf16.h>

// Mamba2 fused block, MI355X. Round 3: bf16 MFMA for GEMM1/GEMM2 (m97-style
// 128x128 tile, global_load_lds width 16, XOR-swizzled staging). Rest as R2.

#define LL 4096
#define DPROJ 4384
#define CONVD 2304
#define DIN 2048
#define NH 32
#define HD 64
#define DS 128
#define CH 256
#define NC 16

typedef unsigned short u16;
typedef unsigned int u32;
typedef __attribute__((ext_vector_type(8))) short bf16x8;
typedef __attribute__((ext_vector_type(4))) float f32x4;

__device__ __forceinline__ float bf2f(u16 v) {
    u32 x = ((u32)v) << 16;
    float f; __builtin_memcpy(&f, &x, 4); return f;
}
__device__ __forceinline__ u16 f2bf(float f) {
    u32 x; __builtin_memcpy(&x, &f, 4);
    u32 r = (x + 0x7fffu + ((x >> 16) & 1u)) >> 16;   // RNE
    return (u16)r;
}
__device__ __forceinline__ float ldin(const void* p, size_t i, int bf) {
    if (bf) return bf2f(((const u16*)p)[i]);
    return ((const float*)p)[i];
}
__device__ __forceinline__ void stout(void* p, size_t i, int bf, float v) {
    if (bf) ((u16*)p)[i] = f2bf(v);
    else    ((float*)p)[i] = v;
}
__device__ __forceinline__ void gll16(const u16* g, u16* l) {
    __builtin_amdgcn_global_load_lds((const u32*)g, (u32*)l, 16, 0, 0);
}

// ---------------- dtype detector ----------------
__global__ void k_detect(const void* u, int* flag) {
    __shared__ int cnt;
    if (threadIdx.x == 0) cnt = 0;
    __syncthreads();
    u16 bits = ((const u16*)u)[2 * threadIdx.x];
    int e = (bits >> 7) & 0xff;
    int ok = (e >= 100 && e <= 141) ? 1 : 0;
    atomicAdd(&cnt, ok);
    __syncthreads();
    if (threadIdx.x == 0) *flag = (cnt > 128) ? 1 : 0;
}

// ---------------- cast to bf16 (identity when input already bf16) ----------------
__global__ void k_cast(const void* src, u16* dst, const int* flagp, int n4) {
    int fl = *flagp;
    size_t i = (size_t)blockIdx.x * 256 + threadIdx.x;
    if (i >= (size_t)n4) return;
    if (fl) {
        ((u32*)dst)[i * 2]     = ((const u32*)src)[i * 2];
        ((u32*)dst)[i * 2 + 1] = ((const u32*)src)[i * 2 + 1];
    } else {
        float4 v = ((const float4*)src)[i];
        dst[i * 4 + 0] = f2bf(v.x); dst[i * 4 + 1] = f2bf(v.y);
        dst[i * 4 + 2] = f2bf(v.z); dst[i * 4 + 3] = f2bf(v.w);
    }
}

// ---------------- transpose + cast: src[R][Cc] -> dst[Cpad][R] bf16, zero-fill ----------------
__global__ __launch_bounds__(256) void k_transpose(const void* src, u16* dst,
                                                   int R, int Cc, const int* flagp) {
    int fl = *flagp;
    __shared__ float tile[32][33];
    int r0 = blockIdx.y * 32, c0 = blockIdx.x * 32;
    int t = threadIdx.x;
    int tr = t >> 5, tc = t & 31;
#pragma unroll
    for (int i = 0; i < 4; ++i) {
        int r = r0 + tr + i * 8, c = c0 + tc;
        float v = 0.f;
        if (c < Cc) v = ldin(src, (size_t)r * Cc + c, fl);
        tile[tr + i * 8][tc] = v;
    }
    __syncthreads();
#pragma unroll
    for (int i = 0; i < 4; ++i) {
        int c = c0 + tr + i * 8, r = r0 + tc;
        dst[(size_t)c * R + r] = f2bf(tile[tc][tr + i * 8]);
    }
}

// ---------------- MFMA GEMM (both operands K-contiguous): C = A[M,K] @ Bt[N,K]^T ----------------
// mode 0: split-store Zb/XBCr/DTraw (GEMM1).  mode 1: store outF per dtype flag (ldc=1024).
__global__ __launch_bounds__(256) void k_gemm_bt(const u16* __restrict__ A, const u16* __restrict__ Bt,
                                                 int K, int mode,
                                                 u16* o0, u16* o1, u16* o2,
                                                 void* outF, const int* flagp) {
    __shared__ __align__(16) u16 sA[4096];
    __shared__ __align__(16) u16 sB[4096];
    int t = threadIdx.x;
    int lane = t & 63, w = t >> 6;
    int wr = w >> 1, wc = w & 1;
    int m0 = blockIdx.y * 128, n0 = blockIdx.x * 128;

    const u16* gA[2]; const u16* gB[2];
    u16* lA[2]; u16* lB[2];
#pragma unroll
    for (int r = 0; r < 2; ++r) {
        int c = w * 128 + r * 64 + lane;
        int m = c >> 2;
        int ks = (c & 3) ^ ((m >> 1) & 3);
        gA[r] = A + (size_t)(m0 + m) * K + ks * 8;
        gB[r] = Bt + (size_t)(n0 + m) * K + ks * 8;
        lA[r] = sA + (size_t)(w * 128 + r * 64) * 8;
        lB[r] = sB + (size_t)(w * 128 + r * 64) * 8;
    }
    int q = lane >> 4, l15 = lane & 15;
    int offA[4], offB[4];
#pragma unroll
    for (int i = 0; i < 4; ++i) {
        int m = wr * 64 + i * 16 + l15;
        offA[i] = (m * 4 + (q ^ ((m >> 1) & 3))) * 8;
        int n = wc * 64 + i * 16 + l15;
        offB[i] = (n * 4 + (q ^ ((n >> 1) & 3))) * 8;
    }
    f32x4 acc[4][4];
#pragma unroll
    for (int i = 0; i < 4; ++i)
#pragma unroll
        for (int j = 0; j < 4; ++j) acc[i][j] = (f32x4){0.f, 0.f, 0.f, 0.f};

    for (int k0 = 0; k0 < K; k0 += 32) {
        gll16(gA[0] + k0, lA[0]);
        gll16(gA[1] + k0, lA[1]);
        gll16(gB[0] + k0, lB[0]);
        gll16(gB[1] + k0, lB[1]);
        __syncthreads();
        bf16x8 af[4], bf[4];
#pragma unroll
        for (int i = 0; i < 4; ++i) af[i] = *(const bf16x8*)(sA + offA[i]);
#pragma unroll
        for (int i = 0; i < 4; ++i) bf[i] = *(const bf16x8*)(sB + offB[i]);
#pragma unroll
        for (int i = 0; i < 4; ++i)
#pragma unroll
            for (int j = 0; j < 4; ++j)
                acc[i][j] = __builtin_amdgcn_mfma_f32_16x16x32_bf16(af[i], bf[j], acc[i][j], 0, 0, 0);
        __syncthreads();
    }

    int fl = (mode == 1) ? *flagp : 0;
#pragma unroll
    for (int i = 0; i < 4; ++i) {
#pragma unroll
        for (int j = 0; j < 4; ++j) {
            int mrow = m0 + wr * 64 + i * 16 + q * 4;
            int n = n0 + wc * 64 + j * 16 + l15;
#pragma unroll
            for (int r = 0; r < 4; ++r) {
                float v = acc[i][j][r];
                size_t m = (size_t)(mrow + r);
                if (mode == 0) {
                    if (n < DIN) o0[m * DIN + n] = f2bf(v);
                    else if (n < DIN + CONVD) o1[m * CONVD + (n - DIN)] = f2bf(v);
                    else if (n < DPROJ) o2[m * NH + (n - DIN - CONVD)] = f2bf(v);
                } else {
                    stout(outF, m * 1024 + n, fl, v);
                }
            }
        }
    }
}

// ---------------- dt softplus + per-chunk cumsum of dA ----------------
__global__ __launch_bounds__(256) void k_dtcum(const u16* DTraw, const void* dtb, const void* alog,
                                               const int* flagp, float* DT, float* ACS, float* AL) {
    int fl = *flagp;
    int bid = blockIdx.x;                 // (b*16+c)*32+h
    int b = bid >> 9, c = (bid >> 5) & 15, h = bid & 31;
    int t = threadIdx.x;
    size_t bl = (size_t)b * LL + c * CH + t;
    float v = bf2f(DTraw[bl * NH + h]) + ldin(dtb, h, fl);
    float sp = (v > 20.f) ? v : log1pf(__expf(v));
    DT[bl * NH + h] = sp;
    float da = -__expf(ldin(alog, h, fl)) * sp;
    __shared__ float sc[256];
    sc[t] = da;
    __syncthreads();
    for (int off = 1; off < 256; off <<= 1) {
        float add = (t >= off) ? sc[t - off] : 0.f;
        __syncthreads();
        sc[t] += add;
        __syncthreads();
    }
    ACS[(size_t)bid * CH + t] = sc[t];
    if (t == 255) AL[bid] = sc[255];
}

// ---------------- causal depthwise conv (width 4) + silu ----------------
__global__ void k_conv(const u16* XBCr, const void* cw, const void* cb, const int* flagp, u16* XCb) {
    int fl = *flagp;
    int ch = blockIdx.x * 256 + threadIdx.x;   // 0..2303 (grid.x = 9)
    size_t bl = blockIdx.y;                    // 0..8191
    int l = (int)(bl & 4095);
    float acc = ldin(cb, ch, fl);
#pragma unroll
    for (int j = 0; j < 4; ++j) {
        int ls = l + j - 3;
        if (ls >= 0)
            acc += bf2f(XBCr[(bl - l + ls) * CONVD + ch]) * ldin(cw, (size_t)ch * 4 + j, fl);
    }
    acc = acc / (1.f + __expf(-acc));
    XCb[bl * CONVD + ch] = f2bf(acc);
}

// ---------------- scores G[l,s] = C[l].B[s] per (b,c) ----------------
__global__ __launch_bounds__(256) void k_scores(const u16* XCb, u16* G) {
    int z = blockIdx.z;   // b*16+c
    const u16* base = XCb + (size_t)z * CH * CONVD;
    __shared__ float As[16][68];
    __shared__ float Bs[16][68];
    int t = threadIdx.x;
    int tx = t & 15, ty = t >> 4;
    int m0 = blockIdx.y * 64, n0 = blockIdx.x * 64;
    float acc[4][4];
#pragma unroll
    for (int i = 0; i < 4; ++i)
#pragma unroll
        for (int j = 0; j < 4; ++j) acc[i][j] = 0.f;

    for (int k0 = 0; k0 < DS; k0 += 16) {
        for (int i = t; i < 1024; i += 256) {
            int m = i >> 4, k = i & 15;
            As[k][m] = bf2f(base[(size_t)(m0 + m) * CONVD + (DIN + DS) + k0 + k]);
        }
        for (int i = t; i < 1024; i += 256) {
            int n = i >> 4, k = i & 15;
            Bs[k][n] = bf2f(base[(size_t)(n0 + n) * CONVD + DIN + k0 + k]);
        }
        __syncthreads();
#pragma unroll
        for (int k = 0; k < 16; ++k) {
            float4 a4 = *(const float4*)&As[k][ty * 4];
            float4 b4 = *(const float4*)&Bs[k][tx * 4];
            float av[4] = {a4.x, a4.y, a4.z, a4.w};
            float bv[4] = {b4.x, b4.y, b4.z, b4.w};
#pragma unroll
            for (int i = 0; i < 4; ++i)
#pragma unroll
                for (int j = 0; j < 4; ++j) acc[i][j] += av[i] * bv[j];
        }
        __syncthreads();
    }
    size_t gb = (size_t)z * 65536;
#pragma unroll
    for (int i = 0; i < 4; ++i) {
        int m = m0 + ty * 4 + i;
#pragma unroll
        for (int j = 0; j < 4; ++j) {
            int n = n0 + tx * 4 + j;
            G[gb + (size_t)m * CH + n] = f2bf(acc[i][j]);
        }
    }
}

// ---------------- per-chunk states ----------------
__global__ __launch_bounds__(256) void k_states(const u16* XCb, const float* DT, const float* ACS,
                                                const float* AL, u16* ST) {
    int bid = blockIdx.x;
    int b = bid >> 9, c = (bid >> 5) & 15, h = bid & 31;
    int t = threadIdx.x;
    size_t bL = (size_t)b * LL + c * CH;
    __shared__ float Xt[32 * 68];
    __shared__ float Bt[32 * 132];
    float al = AL[bid];
    const float* acs = ACS + (size_t)bid * CH;
    float acc[8][4];
#pragma unroll
    for (int j = 0; j < 8; ++j)
#pragma unroll
        for (int i = 0; i < 4; ++i) acc[j][i] = 0.f;
    int p0 = (t & 15) * 4;
    int n0 = (t >> 4) * 8;
    for (int lt = 0; lt < 8; ++lt) {
        int l0 = lt * 32;
        __syncthreads();
        for (int i = t; i < 2048; i += 256) {
            int j = i >> 6, p = i & 63;
            int l = l0 + j;
            float w = __expf(al - acs[l]) * DT[(bL + l) * NH + h];
            Xt[j * 68 + p] = bf2f(XCb[(bL + l) * CONVD + h * HD + p]) * w;
        }
        for (int i = t; i < 4096; i += 256) {
            int j = i >> 7, n = i & 127;
            Bt[j * 132 + n] = bf2f(XCb[(bL + l0 + j) * CONVD + DIN + n]);
        }
        __syncthreads();
#pragma unroll
        for (int l = 0; l < 32; ++l) {
            float4 xv = *(const float4*)&Xt[l * 68 + p0];
            float4 b0 = *(const float4*)&Bt[l * 132 + n0];
            float4 b1 = *(const float4*)&Bt[l * 132 + n0 + 4];
            float bj[8] = {b0.x, b0.y, b0.z, b0.w, b1.x, b1.y, b1.z, b1.w};
            float xi[4] = {xv.x, xv.y, xv.z, xv.w};
#pragma unroll
            for (int j = 0; j < 8; ++j)
#pragma unroll
                for (int i = 0; i < 4; ++i) acc[j][i] += bj[j] * xi[i];
        }
    }
    size_t sbase = (size_t)bid * 8192;
#pragma unroll
    for (int j = 0; j < 8; ++j)
#pragma unroll
        for (int i = 0; i < 4; ++i)
            ST[sbase + (size_t)(n0 + j) * 64 + p0 + i] = f2bf(acc[j][i]);
}

// ---------------- inter-chunk scan (in place; f32 carry in registers) ----------------
__global__ __launch_bounds__(256) void k_scan(const float* AL, u16* ST) {
    int bid = blockIdx.x;  // b*32+h
    int b = bid >> 5, h = bid & 31;
    int t = threadIdx.x;
    float Pv[32];
#pragma unroll
    for (int k = 0; k < 32; ++k) Pv[k] = 0.f;
    for (int c = 0; c < NC; ++c) {
        int bch = (b * NC + c) * NH + h;
        float ga = __expf(AL[bch]);
        size_t base = (size_t)bch * 8192;
#pragma unroll
        for (int k = 0; k < 32; ++k) {
            size_t idx = base + (size_t)k * 256 + t;
            float s = bf2f(ST[idx]);
            ST[idx] = f2bf(Pv[k]);
            Pv[k] = ga * Pv[k] + s;
        }
    }
}

// ---------------- Y = Y_off + Y_diag ----------------
__global__ __launch_bounds__(256) void k_ydiag(const u16* XCb, const float* DT, const float* ACS,
                                               const u16* G, const u16* ST, u16* Yb) {
    int bid = blockIdx.x;
    int b = bid >> 9, c = (bid >> 5) & 15, h = bid & 31;
    int t = threadIdx.x;
    size_t bL = (size_t)b * LL + c * CH;
    size_t gbase = (size_t)(b * NC + c) * 65536;
    size_t pbase = (size_t)bid * 8192;
    __shared__ float acs_s[256];
    __shared__ char smem[52224];
    float* Pl = (float*)smem;            // 128 x 68
    float* Ct = (float*)(smem + 34816);  // 256 x 17
    float* Gt = (float*)smem;            // 256 x 33 (phase B)
    float* Xt = (float*)(smem + 33792);  // 32 x 68  (phase B)

    acs_s[t] = ACS[(size_t)bid * CH + t];
    for (int i = t; i < 8192; i += 256)
        Pl[(i >> 6) * 68 + (i & 63)] = bf2f(ST[pbase + i]);  // [n][p]
    __syncthreads();
    float myA = acs_s[t];
    float accp[64];
#pragma unroll
    for (int i = 0; i < 64; ++i) accp[i] = 0.f;

    for (int nt = 0; nt < 8; ++nt) {
        __syncthreads();
        for (int i = t; i < 4096; i += 256) {
            int row = i >> 4, col = i & 15;
            Ct[row * 17 + col] = bf2f(XCb[(bL + row) * CONVD + DIN + DS + nt * 16 + col]);
        }
        __syncthreads();
#pragma unroll
        for (int j = 0; j < 16; ++j) {
            float cf = Ct[t * 17 + j];
            const float4* pr = (const float4*)&Pl[(nt * 16 + j) * 68];
#pragma unroll
            for (int q = 0; q < 16; ++q) {
                float4 pv = pr[q];
                accp[q * 4 + 0] += cf * pv.x; accp[q * 4 + 1] += cf * pv.y;
                accp[q * 4 + 2] += cf * pv.z; accp[q * 4 + 3] += cf * pv.w;
            }
        }
    }
    float od = __expf(myA);
#pragma unroll
    for (int i = 0; i < 64; ++i) accp[i] *= od;

    for (int st8 = 0; st8 < 8; ++st8) {
        int s0 = st8 * 32;
        __syncthreads();
        for (int i = t; i < 8192; i += 256) {
            int row = i >> 5, col = i & 31;
            Gt[row * 33 + col] = bf2f(G[gbase + (size_t)row * 256 + s0 + col]);
        }
        for (int i = t; i < 2048; i += 256) {
            int j = i >> 6, p = i & 63;
            int s = s0 + j;
            Xt[j * 68 + p] = bf2f(XCb[(bL + s) * CONVD + h * HD + p]) * DT[(bL + s) * NH + h];
        }
        __syncthreads();
        if (t >= s0) {
            int jmax = t - s0; if (jmax > 31) jmax = 31;
            for (int j = 0; j <= jmax; ++j) {
                float cf = Gt[t * 33 + j] * __expf(myA - acs_s[s0 + j]);
                const float4* xr = (const float4*)&Xt[j * 68];
#pragma unroll
                for (int q = 0; q < 16; ++q) {
                    float4 xv = xr[q];
                    accp[q * 4 + 0] += cf * xv.x; accp[q * 4 + 1] += cf * xv.y;
                    accp[q * 4 + 2] += cf * xv.z; accp[q * 4 + 3] += cf * xv.w;
                }
            }
        }
    }
    size_t ybase = (bL + t) * (size_t)DIN + h * HD;
    u32* yo = (u32*)&Yb[ybase];
#pragma unroll
    for (int q = 0; q < 32; ++q)
        yo[q] = (u32)f2bf(accp[2 * q]) | ((u32)f2bf(accp[2 * q + 1]) << 16);
}

// ---------------- layernorm * silu(z), in place on Yb ----------------
__global__ __launch_bounds__(256) void k_norm(u16* Yb, const u16* Zb, const void* nw, const int* flagp) {
    int fl = *flagp;
    size_t row = blockIdx.x;
    int t = threadIdx.x;
    size_t base = row * (size_t)DIN;
    float v[8];
#pragma unroll
    for (int k = 0; k < 8; ++k) v[k] = bf2f(Yb[base + k * 256 + t]);
    float s = 0.f;
#pragma unroll
    for (int k = 0; k < 8; ++k) s += v[k];
#pragma unroll
    for (int off = 32; off > 0; off >>= 1) s += __shfl_down(s, off);
    __shared__ float red[4];
    int wid = t >> 6, lid = t & 63;
    if (lid == 0) red[wid] = s;
    __syncthreads();
    float mu = (red[0] + red[1] + red[2] + red[3]) * (1.f / 2048.f);
    float d = 0.f;
#pragma unroll
    for (int k = 0; k < 8; ++k) { float e = v[k] - mu; d += e * e; }
#pragma unroll
    for (int off = 32; off > 0; off >>= 1) d += __shfl_down(d, off);
    __syncthreads();
    if (lid == 0) red[wid] = d;
    __syncthreads();
    float var = (red[0] + red[1] + red[2] + red[3]) * (1.f / 2048.f);
    float rs = rsqrtf(var + 1e-5f);
#pragma unroll
    for (int k = 0; k < 8; ++k) {
        int dcol = k * 256 + t;
        float z = bf2f(Zb[row * DIN + dcol]);
        float sz = z / (1.f + __expf(-z));
        Yb[base + dcol] = f2bf((v[k] - mu) * rs * ldin(nw, dcol, fl) * sz);
    }
}

extern "C" void kernel_launch(void* const* d_in, const int* in_sizes, int n_in,
                              void* d_out, int out_size, void* d_ws, size_t ws_size,
                              hipStream_t stream) {
    const void* u    = d_in[0];
    const void* Win  = d_in[1];
    const void* cw   = d_in[2];
    const void* cb   = d_in[3];
    const void* dtb  = d_in[4];
    const void* alog = d_in[5];
    const void* nw   = d_in[6];
    const void* Wout = d_in[7];

    char* base = (char*)d_ws;
    int*  flag  = (int*)base;
    u16*  Zb    = (u16*)(base + 256);               // 33,554,432 B
    u16*  XBCr  = (u16*)(base + 33554688);          // 37,748,736 B (Yb aliases)
    u16*  XCb   = (u16*)(base + 71303424);          // 37,748,736 B (Ub/WinT alias)
    u16*  ST    = (u16*)(base + 109052160);         // 16,777,216 B (WoutT aliases)
    u16*  G     = (u16*)(base + 125829376);         //  4,194,304 B
    float* DT   = (float*)(base + 130023680);       //  1,048,576 B
    float* ACS  = (float*)(base + 131072256);       //  1,048,576 B
    float* AL   = (float*)(base + 132120832);       //      4,096 B
    u16*  DTraw = (u16*)(base + 132124928);         //    524,288 B  (end 132,649,216)
    u16*  Yb    = XBCr;                             // alias: XBCr dead after conv
    u16*  Ub    = (u16*)(base + 71303424);          // alias into XCb region (pre-conv)
    u16*  WinT  = (u16*)(base + 88080640);          // alias into XCb region (pre-conv)
    u16*  WoutT = (u16*)(base + 109052160);         // alias onto ST (post-ydiag)

    k_detect<<<1, 256, 0, stream>>>(u, flag);
    // bf16 operand prep
    k_cast<<<8192, 256, 0, stream>>>(u, Ub, flag, 2097152);               // u [8192,1024]
    k_transpose<<<dim3(140, 32), 256, 0, stream>>>(Win, WinT, 1024, 4384, flag);  // -> [4480][1024]
    // GEMM1 (MFMA): zxbcdt split
    k_gemm_bt<<<dim3(35, 64), 256, 0, stream>>>(Ub, WinT, 1024, 0, Zb, XBCr, DTraw, nullptr, flag);
    k_dtcum<<<1024, 256, 0, stream>>>(DTraw, dtb, alog, flag, DT, ACS, AL);
    k_conv<<<dim3(9, 8192), 256, 0, stream>>>(XBCr, cw, cb, flag, XCb);
    k_scores<<<dim3(4, 4, 32), 256, 0, stream>>>(XCb, G);
    k_states<<<1024, 256, 0, stream>>>(XCb, DT, ACS, AL, ST);
    k_scan<<<64, 256, 0, stream>>>(AL, ST);
    k_ydiag<<<1024, 256, 0, stream>>>(XCb, DT, ACS, G, ST, Yb);
    k_transpose<<<dim3(32, 64), 256, 0, stream>>>(Wout, WoutT, 2048, 1024, flag); // -> [1024][2048]
    k_norm<<<8192, 256, 0, stream>>>(Yb, Zb, nw, flag);
    // GEMM2 (MFMA): out = Yb @ Wout
    k_gemm_bt<<<dim3(8, 64), 256, 0, stream>>>(Yb, WoutT, 2048, 1, nullptr, nullptr, nullptr, d_out, flag);
}

// Round 4
// 881.754 us; speedup vs baseline: 2.7443x; 1.0085x over previous
//
#include <hip/hip_runtime.h>
#include <hip/hip_bf16.h>

// Mamba2 fused block, MI355X. Round 4: MFMA-ized k_ydiag (K-tiled [256x384]@[384x64]
// per (b,c,h): masked-decay scores + state offload in one accumulator). GEMMs as R3.

#define LL 4096
#define DPROJ 4384
#define CONVD 2304
#define DIN 2048
#define NH 32
#define HD 64
#define DS 128
#define CH 256
#define NC 16

typedef unsigned short u16;
typedef unsigned int u32;
typedef __attribute__((ext_vector_type(8))) short bf16x8;
typedef __attribute__((ext_vector_type(4))) float f32x4;

__device__ __forceinline__ float bf2f(u16 v) {
    u32 x = ((u32)v) << 16;
    float f; __builtin_memcpy(&f, &x, 4); return f;
}
__device__ __forceinline__ u16 f2bf(float f) {
    u32 x; __builtin_memcpy(&x, &f, 4);
    u32 r = (x + 0x7fffu + ((x >> 16) & 1u)) >> 16;   // RNE
    return (u16)r;
}
__device__ __forceinline__ float ldin(const void* p, size_t i, int bf) {
    if (bf) return bf2f(((const u16*)p)[i]);
    return ((const float*)p)[i];
}
__device__ __forceinline__ void stout(void* p, size_t i, int bf, float v) {
    if (bf) ((u16*)p)[i] = f2bf(v);
    else    ((float*)p)[i] = v;
}
__device__ __forceinline__ void gll16(const u16* g, u16* l) {
    __builtin_amdgcn_global_load_lds((const u32*)g, (u32*)l, 16, 0, 0);
}

// ---------------- dtype detector ----------------
__global__ void k_detect(const void* u, int* flag) {
    __shared__ int cnt;
    if (threadIdx.x == 0) cnt = 0;
    __syncthreads();
    u16 bits = ((const u16*)u)[2 * threadIdx.x];
    int e = (bits >> 7) & 0xff;
    int ok = (e >= 100 && e <= 141) ? 1 : 0;
    atomicAdd(&cnt, ok);
    __syncthreads();
    if (threadIdx.x == 0) *flag = (cnt > 128) ? 1 : 0;
}

// ---------------- cast to bf16 (identity when input already bf16) ----------------
__global__ void k_cast(const void* src, u16* dst, const int* flagp, int n4) {
    int fl = *flagp;
    size_t i = (size_t)blockIdx.x * 256 + threadIdx.x;
    if (i >= (size_t)n4) return;
    if (fl) {
        ((u32*)dst)[i * 2]     = ((const u32*)src)[i * 2];
        ((u32*)dst)[i * 2 + 1] = ((const u32*)src)[i * 2 + 1];
    } else {
        float4 v = ((const float4*)src)[i];
        dst[i * 4 + 0] = f2bf(v.x); dst[i * 4 + 1] = f2bf(v.y);
        dst[i * 4 + 2] = f2bf(v.z); dst[i * 4 + 3] = f2bf(v.w);
    }
}

// ---------------- transpose + cast: src[R][Cc] -> dst[Cpad][R] bf16, zero-fill ----------------
__global__ __launch_bounds__(256) void k_transpose(const void* src, u16* dst,
                                                   int R, int Cc, const int* flagp) {
    int fl = *flagp;
    __shared__ float tile[32][33];
    int r0 = blockIdx.y * 32, c0 = blockIdx.x * 32;
    int t = threadIdx.x;
    int tr = t >> 5, tc = t & 31;
#pragma unroll
    for (int i = 0; i < 4; ++i) {
        int r = r0 + tr + i * 8, c = c0 + tc;
        float v = 0.f;
        if (c < Cc) v = ldin(src, (size_t)r * Cc + c, fl);
        tile[tr + i * 8][tc] = v;
    }
    __syncthreads();
#pragma unroll
    for (int i = 0; i < 4; ++i) {
        int c = c0 + tr + i * 8, r = r0 + tc;
        dst[(size_t)c * R + r] = f2bf(tile[tc][tr + i * 8]);
    }
}

// ---------------- MFMA GEMM (both operands K-contiguous): C = A[M,K] @ Bt[N,K]^T ----------------
__global__ __launch_bounds__(256) void k_gemm_bt(const u16* __restrict__ A, const u16* __restrict__ Bt,
                                                 int K, int mode,
                                                 u16* o0, u16* o1, u16* o2,
                                                 void* outF, const int* flagp) {
    __shared__ __align__(16) u16 sA[4096];
    __shared__ __align__(16) u16 sB[4096];
    int t = threadIdx.x;
    int lane = t & 63, w = t >> 6;
    int wr = w >> 1, wc = w & 1;
    int m0 = blockIdx.y * 128, n0 = blockIdx.x * 128;

    const u16* gA[2]; const u16* gB[2];
    u16* lA[2]; u16* lB[2];
#pragma unroll
    for (int r = 0; r < 2; ++r) {
        int c = w * 128 + r * 64 + lane;
        int m = c >> 2;
        int ks = (c & 3) ^ ((m >> 1) & 3);
        gA[r] = A + (size_t)(m0 + m) * K + ks * 8;
        gB[r] = Bt + (size_t)(n0 + m) * K + ks * 8;
        lA[r] = sA + (size_t)(w * 128 + r * 64) * 8;
        lB[r] = sB + (size_t)(w * 128 + r * 64) * 8;
    }
    int q = lane >> 4, l15 = lane & 15;
    int offA[4], offB[4];
#pragma unroll
    for (int i = 0; i < 4; ++i) {
        int m = wr * 64 + i * 16 + l15;
        offA[i] = (m * 4 + (q ^ ((m >> 1) & 3))) * 8;
        int n = wc * 64 + i * 16 + l15;
        offB[i] = (n * 4 + (q ^ ((n >> 1) & 3))) * 8;
    }
    f32x4 acc[4][4];
#pragma unroll
    for (int i = 0; i < 4; ++i)
#pragma unroll
        for (int j = 0; j < 4; ++j) acc[i][j] = (f32x4){0.f, 0.f, 0.f, 0.f};

    for (int k0 = 0; k0 < K; k0 += 32) {
        gll16(gA[0] + k0, lA[0]);
        gll16(gA[1] + k0, lA[1]);
        gll16(gB[0] + k0, lB[0]);
        gll16(gB[1] + k0, lB[1]);
        __syncthreads();
        bf16x8 af[4], bfv[4];
#pragma unroll
        for (int i = 0; i < 4; ++i) af[i] = *(const bf16x8*)(sA + offA[i]);
#pragma unroll
        for (int i = 0; i < 4; ++i) bfv[i] = *(const bf16x8*)(sB + offB[i]);
#pragma unroll
        for (int i = 0; i < 4; ++i)
#pragma unroll
            for (int j = 0; j < 4; ++j)
                acc[i][j] = __builtin_amdgcn_mfma_f32_16x16x32_bf16(af[i], bfv[j], acc[i][j], 0, 0, 0);
        __syncthreads();
    }

    int fl = (mode == 1) ? *flagp : 0;
#pragma unroll
    for (int i = 0; i < 4; ++i) {
#pragma unroll
        for (int j = 0; j < 4; ++j) {
            int mrow = m0 + wr * 64 + i * 16 + q * 4;
            int n = n0 + wc * 64 + j * 16 + l15;
#pragma unroll
            for (int r = 0; r < 4; ++r) {
                float v = acc[i][j][r];
                size_t m = (size_t)(mrow + r);
                if (mode == 0) {
                    if (n < DIN) o0[m * DIN + n] = f2bf(v);
                    else if (n < DIN + CONVD) o1[m * CONVD + (n - DIN)] = f2bf(v);
                    else if (n < DPROJ) o2[m * NH + (n - DIN - CONVD)] = f2bf(v);
                } else {
                    stout(outF, m * 1024 + n, fl, v);
                }
            }
        }
    }
}

// ---------------- dt softplus + per-chunk cumsum of dA ----------------
__global__ __launch_bounds__(256) void k_dtcum(const u16* DTraw, const void* dtb, const void* alog,
                                               const int* flagp, float* DT, float* ACS, float* AL) {
    int fl = *flagp;
    int bid = blockIdx.x;                 // (b*16+c)*32+h
    int b = bid >> 9, c = (bid >> 5) & 15, h = bid & 31;
    int t = threadIdx.x;
    size_t bl = (size_t)b * LL + c * CH + t;
    float v = bf2f(DTraw[bl * NH + h]) + ldin(dtb, h, fl);
    float sp = (v > 20.f) ? v : log1pf(__expf(v));
    DT[bl * NH + h] = sp;
    float da = -__expf(ldin(alog, h, fl)) * sp;
    __shared__ float sc[256];
    sc[t] = da;
    __syncthreads();
    for (int off = 1; off < 256; off <<= 1) {
        float add = (t >= off) ? sc[t - off] : 0.f;
        __syncthreads();
        sc[t] += add;
        __syncthreads();
    }
    ACS[(size_t)bid * CH + t] = sc[t];
    if (t == 255) AL[bid] = sc[255];
}

// ---------------- causal depthwise conv (width 4) + silu ----------------
__global__ void k_conv(const u16* XBCr, const void* cw, const void* cb, const int* flagp, u16* XCb) {
    int fl = *flagp;
    int ch = blockIdx.x * 256 + threadIdx.x;   // 0..2303 (grid.x = 9)
    size_t bl = blockIdx.y;                    // 0..8191
    int l = (int)(bl & 4095);
    float acc = ldin(cb, ch, fl);
#pragma unroll
    for (int j = 0; j < 4; ++j) {
        int ls = l + j - 3;
        if (ls >= 0)
            acc += bf2f(XBCr[(bl - l + ls) * CONVD + ch]) * ldin(cw, (size_t)ch * 4 + j, fl);
    }
    acc = acc / (1.f + __expf(-acc));
    XCb[bl * CONVD + ch] = f2bf(acc);
}

// ---------------- scores G[l,s] = C[l].B[s] per (b,c) ----------------
__global__ __launch_bounds__(256) void k_scores(const u16* XCb, u16* G) {
    int z = blockIdx.z;   // b*16+c
    const u16* base = XCb + (size_t)z * CH * CONVD;
    __shared__ float As[16][68];
    __shared__ float Bs[16][68];
    int t = threadIdx.x;
    int tx = t & 15, ty = t >> 4;
    int m0 = blockIdx.y * 64, n0 = blockIdx.x * 64;
    float acc[4][4];
#pragma unroll
    for (int i = 0; i < 4; ++i)
#pragma unroll
        for (int j = 0; j < 4; ++j) acc[i][j] = 0.f;

    for (int k0 = 0; k0 < DS; k0 += 16) {
        for (int i = t; i < 1024; i += 256) {
            int m = i >> 4, k = i & 15;
            As[k][m] = bf2f(base[(size_t)(m0 + m) * CONVD + (DIN + DS) + k0 + k]);
        }
        for (int i = t; i < 1024; i += 256) {
            int n = i >> 4, k = i & 15;
            Bs[k][n] = bf2f(base[(size_t)(n0 + n) * CONVD + DIN + k0 + k]);
        }
        __syncthreads();
#pragma unroll
        for (int k = 0; k < 16; ++k) {
            float4 a4 = *(const float4*)&As[k][ty * 4];
            float4 b4 = *(const float4*)&Bs[k][tx * 4];
            float av[4] = {a4.x, a4.y, a4.z, a4.w};
            float bv[4] = {b4.x, b4.y, b4.z, b4.w};
#pragma unroll
            for (int i = 0; i < 4; ++i)
#pragma unroll
                for (int j = 0; j < 4; ++j) acc[i][j] += av[i] * bv[j];
        }
        __syncthreads();
    }
    size_t gb = (size_t)z * 65536;
#pragma unroll
    for (int i = 0; i < 4; ++i) {
        int m = m0 + ty * 4 + i;
#pragma unroll
        for (int j = 0; j < 4; ++j) {
            int n = n0 + tx * 4 + j;
            G[gb + (size_t)m * CH + n] = f2bf(acc[i][j]);
        }
    }
}

// ---------------- per-chunk states ----------------
__global__ __launch_bounds__(256) void k_states(const u16* XCb, const float* DT, const float* ACS,
                                                const float* AL, u16* ST) {
    int bid = blockIdx.x;
    int b = bid >> 9, c = (bid >> 5) & 15, h = bid & 31;
    int t = threadIdx.x;
    size_t bL = (size_t)b * LL + c * CH;
    __shared__ float Xt[32 * 68];
    __shared__ float Bt[32 * 132];
    float al = AL[bid];
    const float* acs = ACS + (size_t)bid * CH;
    float acc[8][4];
#pragma unroll
    for (int j = 0; j < 8; ++j)
#pragma unroll
        for (int i = 0; i < 4; ++i) acc[j][i] = 0.f;
    int p0 = (t & 15) * 4;
    int n0 = (t >> 4) * 8;
    for (int lt = 0; lt < 8; ++lt) {
        int l0 = lt * 32;
        __syncthreads();
        for (int i = t; i < 2048; i += 256) {
            int j = i >> 6, p = i & 63;
            int l = l0 + j;
            float w = __expf(al - acs[l]) * DT[(bL + l) * NH + h];
            Xt[j * 68 + p] = bf2f(XCb[(bL + l) * CONVD + h * HD + p]) * w;
        }
        for (int i = t; i < 4096; i += 256) {
            int j = i >> 7, n = i & 127;
            Bt[j * 132 + n] = bf2f(XCb[(bL + l0 + j) * CONVD + DIN + n]);
        }
        __syncthreads();
#pragma unroll
        for (int l = 0; l < 32; ++l) {
            float4 xv = *(const float4*)&Xt[l * 68 + p0];
            float4 b0 = *(const float4*)&Bt[l * 132 + n0];
            float4 b1 = *(const float4*)&Bt[l * 132 + n0 + 4];
            float bj[8] = {b0.x, b0.y, b0.z, b0.w, b1.x, b1.y, b1.z, b1.w};
            float xi[4] = {xv.x, xv.y, xv.z, xv.w};
#pragma unroll
            for (int j = 0; j < 8; ++j)
#pragma unroll
                for (int i = 0; i < 4; ++i) acc[j][i] += bj[j] * xi[i];
        }
    }
    size_t sbase = (size_t)bid * 8192;
#pragma unroll
    for (int j = 0; j < 8; ++j)
#pragma unroll
        for (int i = 0; i < 4; ++i)
            ST[sbase + (size_t)(n0 + j) * 64 + p0 + i] = f2bf(acc[j][i]);
}

// ---------------- inter-chunk scan (in place; f32 carry in registers) ----------------
__global__ __launch_bounds__(256) void k_scan(const float* AL, u16* ST) {
    int bid = blockIdx.x;  // b*32+h
    int b = bid >> 5, h = bid & 31;
    int t = threadIdx.x;
    float Pv[32];
#pragma unroll
    for (int k = 0; k < 32; ++k) Pv[k] = 0.f;
    for (int c = 0; c < NC; ++c) {
        int bch = (b * NC + c) * NH + h;
        float ga = __expf(AL[bch]);
        size_t base = (size_t)bch * 8192;
#pragma unroll
        for (int k = 0; k < 32; ++k) {
            size_t idx = base + (size_t)k * 256 + t;
            float s = bf2f(ST[idx]);
            ST[idx] = f2bf(Pv[k]);
            Pv[k] = ga * Pv[k] + s;
        }
    }
}

// ---------------- Y = Y_off + Y_diag via MFMA: [256 x 384] @ [384 x 64] per (b,c,h) ----------------
__global__ __launch_bounds__(256) void k_ydiag(const u16* XCb, const float* DT, const float* ACS,
                                               const u16* G, const u16* ST, u16* Yb) {
    int bid = blockIdx.x;
    int b = bid >> 9, c = (bid >> 5) & 15, h = bid & 31;
    int t = threadIdx.x;
    size_t bL = (size_t)b * LL + c * CH;
    size_t gbase = (size_t)(b * NC + c) * 65536;
    size_t pbase = (size_t)bid * 8192;
    __shared__ float acs_s[256];
    __shared__ float ea_s[256];
    __shared__ __align__(16) u16 Wt[256 * 40];   // A-tile, K-contiguous rows (pad 40)
    __shared__ __align__(16) u16 Pt[64 * 40];    // B-tile: [p][k] K-contiguous

    float a0 = ACS[(size_t)bid * CH + t];
    acs_s[t] = a0;
    ea_s[t] = __expf(a0);
    __syncthreads();

    int lane = t & 63, w = t >> 6;
    int q = lane >> 4, l15 = lane & 15;
    int tr = t >> 5;   // 0..7
    int tc = t & 31;   // 0..31

    f32x4 acc[4][4];
#pragma unroll
    for (int i = 0; i < 4; ++i)
#pragma unroll
        for (int j = 0; j < 4; ++j) acc[i][j] = (f32x4){0.f, 0.f, 0.f, 0.f};

    for (int kt = 0; kt < 12; ++kt) {
        if (kt < 8) {
            // diag part: A = G .* mask .* exp(A[l]-A[s]);  B = X[s,p]*dt[s]
            int s0 = kt * 32;
            int s = s0 + tc;
            float as = acs_s[s];
#pragma unroll
            for (int e = 0; e < 32; ++e) {
                int l = e * 8 + tr;
                float wv = 0.f;
                if (l >= s) {
                    float g = bf2f(G[gbase + (size_t)l * 256 + s]);
                    wv = g * __expf(acs_s[l] - as);
                }
                Wt[l * 40 + tc] = f2bf(wv);
            }
#pragma unroll
            for (int e = 0; e < 8; ++e) {
                int i = e * 256 + t;
                int sl = i >> 6, p = i & 63;
                int s2 = s0 + sl;
                float v = bf2f(XCb[(bL + s2) * CONVD + h * HD + p]) * DT[(bL + s2) * NH + h];
                Pt[p * 40 + sl] = f2bf(v);
            }
        } else {
            // off part: A = C[l,n]*exp(A[l]);  B = P[n,p]
            int n0 = (kt - 8) * 32;
            int n = n0 + tc;
#pragma unroll
            for (int e = 0; e < 32; ++e) {
                int l = e * 8 + tr;
                float v = bf2f(XCb[(bL + l) * CONVD + DIN + DS + n]) * ea_s[l];
                Wt[l * 40 + tc] = f2bf(v);
            }
#pragma unroll
            for (int e = 0; e < 8; ++e) {
                int i = e * 256 + t;
                int nl = i >> 6, p = i & 63;
                float v = bf2f(ST[pbase + (size_t)(n0 + nl) * 64 + p]);
                Pt[p * 40 + nl] = f2bf(v);
            }
        }
        __syncthreads();
        bf16x8 af[4], bfv[4];
#pragma unroll
        for (int i = 0; i < 4; ++i)
            af[i] = *(const bf16x8*)&Wt[(w * 64 + i * 16 + l15) * 40 + q * 8];
#pragma unroll
        for (int j = 0; j < 4; ++j)
            bfv[j] = *(const bf16x8*)&Pt[(j * 16 + l15) * 40 + q * 8];
#pragma unroll
        for (int i = 0; i < 4; ++i)
#pragma unroll
            for (int j = 0; j < 4; ++j)
                acc[i][j] = __builtin_amdgcn_mfma_f32_16x16x32_bf16(af[i], bfv[j], acc[i][j], 0, 0, 0);
        __syncthreads();
    }

#pragma unroll
    for (int i = 0; i < 4; ++i) {
        int lrow = w * 64 + i * 16 + q * 4;
#pragma unroll
        for (int j = 0; j < 4; ++j) {
            int p = j * 16 + l15;
#pragma unroll
            for (int r = 0; r < 4; ++r)
                Yb[(bL + lrow + r) * (size_t)DIN + h * HD + p] = f2bf(acc[i][j][r]);
        }
    }
}

// ---------------- layernorm * silu(z), in place on Yb ----------------
__global__ __launch_bounds__(256) void k_norm(u16* Yb, const u16* Zb, const void* nw, const int* flagp) {
    int fl = *flagp;
    size_t row = blockIdx.x;
    int t = threadIdx.x;
    size_t base = row * (size_t)DIN;
    float v[8];
#pragma unroll
    for (int k = 0; k < 8; ++k) v[k] = bf2f(Yb[base + k * 256 + t]);
    float s = 0.f;
#pragma unroll
    for (int k = 0; k < 8; ++k) s += v[k];
#pragma unroll
    for (int off = 32; off > 0; off >>= 1) s += __shfl_down(s, off);
    __shared__ float red[4];
    int wid = t >> 6, lid = t & 63;
    if (lid == 0) red[wid] = s;
    __syncthreads();
    float mu = (red[0] + red[1] + red[2] + red[3]) * (1.f / 2048.f);
    float d = 0.f;
#pragma unroll
    for (int k = 0; k < 8; ++k) { float e = v[k] - mu; d += e * e; }
#pragma unroll
    for (int off = 32; off > 0; off >>= 1) d += __shfl_down(d, off);
    __syncthreads();
    if (lid == 0) red[wid] = d;
    __syncthreads();
    float var = (red[0] + red[1] + red[2] + red[3]) * (1.f / 2048.f);
    float rs = rsqrtf(var + 1e-5f);
#pragma unroll
    for (int k = 0; k < 8; ++k) {
        int dcol = k * 256 + t;
        float z = bf2f(Zb[row * DIN + dcol]);
        float sz = z / (1.f + __expf(-z));
        Yb[base + dcol] = f2bf((v[k] - mu) * rs * ldin(nw, dcol, fl) * sz);
    }
}

extern "C" void kernel_launch(void* const* d_in, const int* in_sizes, int n_in,
                              void* d_out, int out_size, void* d_ws, size_t ws_size,
                              hipStream_t stream) {
    const void* u    = d_in[0];
    const void* Win  = d_in[1];
    const void* cw   = d_in[2];
    const void* cb   = d_in[3];
    const void* dtb  = d_in[4];
    const void* alog = d_in[5];
    const void* nw   = d_in[6];
    const void* Wout = d_in[7];

    char* base = (char*)d_ws;
    int*  flag  = (int*)base;
    u16*  Zb    = (u16*)(base + 256);               // 33,554,432 B
    u16*  XBCr  = (u16*)(base + 33554688);          // 37,748,736 B (Yb aliases)
    u16*  XCb   = (u16*)(base + 71303424);          // 37,748,736 B (Ub/WinT alias)
    u16*  ST    = (u16*)(base + 109052160);         // 16,777,216 B (WoutT aliases)
    u16*  G     = (u16*)(base + 125829376);         //  4,194,304 B
    float* DT   = (float*)(base + 130023680);       //  1,048,576 B
    float* ACS  = (float*)(base + 131072256);       //  1,048,576 B
    float* AL   = (float*)(base + 132120832);       //      4,096 B
    u16*  DTraw = (u16*)(base + 132124928);         //    524,288 B  (end 132,649,216)
    u16*  Yb    = XBCr;                             // alias: XBCr dead after conv
    u16*  Ub    = (u16*)(base + 71303424);          // alias into XCb region (pre-conv)
    u16*  WinT  = (u16*)(base + 88080640);          // alias into XCb region (pre-conv)
    u16*  WoutT = (u16*)(base + 109052160);         // alias onto ST (post-ydiag)

    k_detect<<<1, 256, 0, stream>>>(u, flag);
    k_cast<<<8192, 256, 0, stream>>>(u, Ub, flag, 2097152);
    k_transpose<<<dim3(140, 32), 256, 0, stream>>>(Win, WinT, 1024, 4384, flag);
    k_gemm_bt<<<dim3(35, 64), 256, 0, stream>>>(Ub, WinT, 1024, 0, Zb, XBCr, DTraw, nullptr, flag);
    k_dtcum<<<1024, 256, 0, stream>>>(DTraw, dtb, alog, flag, DT, ACS, AL);
    k_conv<<<dim3(9, 8192), 256, 0, stream>>>(XBCr, cw, cb, flag, XCb);
    k_scores<<<dim3(4, 4, 32), 256, 0, stream>>>(XCb, G);
    k_states<<<1024, 256, 0, stream>>>(XCb, DT, ACS, AL, ST);
    k_scan<<<64, 256, 0, stream>>>(AL, ST);
    k_ydiag<<<1024, 256, 0, stream>>>(XCb, DT, ACS, G, ST, Yb);
    k_transpose<<<dim3(32, 64), 256, 0, stream>>>(Wout, WoutT, 2048, 1024, flag);
    k_norm<<<8192, 256, 0, stream>>>(Yb, Zb, nw, flag);
    k_gemm_bt<<<dim3(8, 64), 256, 0, stream>>>(Yb, WoutT, 2048, 1, nullptr, nullptr, nullptr, d_out, flag);
}

// Round 5
// 692.658 us; speedup vs baseline: 3.4934x; 1.2730x over previous
//
#include <hip/hip_runtime.h>
#include <hip/hip_bf16.h>

// Mamba2 fused block, MI355X. Round 5: ydiag split-l (4096 blocks) + factored
// decay exp + pad-38 LDS; states MFMA-ized (output [p][n]). GEMMs as R3/R4.

#define LL 4096
#define DPROJ 4384
#define CONVD 2304
#define DIN 2048
#define NH 32
#define HD 64
#define DS 128
#define CH 256
#define NC 16

typedef unsigned short u16;
typedef unsigned int u32;
typedef __attribute__((ext_vector_type(8))) short bf16x8;
typedef __attribute__((ext_vector_type(4))) float f32x4;

__device__ __forceinline__ float bf2f(u16 v) {
    u32 x = ((u32)v) << 16;
    float f; __builtin_memcpy(&f, &x, 4); return f;
}
__device__ __forceinline__ u16 f2bf(float f) {
    u32 x; __builtin_memcpy(&x, &f, 4);
    u32 r = (x + 0x7fffu + ((x >> 16) & 1u)) >> 16;   // RNE
    return (u16)r;
}
__device__ __forceinline__ float ldin(const void* p, size_t i, int bf) {
    if (bf) return bf2f(((const u16*)p)[i]);
    return ((const float*)p)[i];
}
__device__ __forceinline__ void stout(void* p, size_t i, int bf, float v) {
    if (bf) ((u16*)p)[i] = f2bf(v);
    else    ((float*)p)[i] = v;
}
__device__ __forceinline__ void gll16(const u16* g, u16* l) {
    __builtin_amdgcn_global_load_lds((const u32*)g, (u32*)l, 16, 0, 0);
}

// ---------------- dtype detector ----------------
__global__ void k_detect(const void* u, int* flag) {
    __shared__ int cnt;
    if (threadIdx.x == 0) cnt = 0;
    __syncthreads();
    u16 bits = ((const u16*)u)[2 * threadIdx.x];
    int e = (bits >> 7) & 0xff;
    int ok = (e >= 100 && e <= 141) ? 1 : 0;
    atomicAdd(&cnt, ok);
    __syncthreads();
    if (threadIdx.x == 0) *flag = (cnt > 128) ? 1 : 0;
}

// ---------------- cast to bf16 (identity when input already bf16) ----------------
__global__ void k_cast(const void* src, u16* dst, const int* flagp, int n4) {
    int fl = *flagp;
    size_t i = (size_t)blockIdx.x * 256 + threadIdx.x;
    if (i >= (size_t)n4) return;
    if (fl) {
        ((u32*)dst)[i * 2]     = ((const u32*)src)[i * 2];
        ((u32*)dst)[i * 2 + 1] = ((const u32*)src)[i * 2 + 1];
    } else {
        float4 v = ((const float4*)src)[i];
        dst[i * 4 + 0] = f2bf(v.x); dst[i * 4 + 1] = f2bf(v.y);
        dst[i * 4 + 2] = f2bf(v.z); dst[i * 4 + 3] = f2bf(v.w);
    }
}

// ---------------- transpose + cast: src[R][Cc] -> dst[Cpad][R] bf16, zero-fill ----------------
__global__ __launch_bounds__(256) void k_transpose(const void* src, u16* dst,
                                                   int R, int Cc, const int* flagp) {
    int fl = *flagp;
    __shared__ float tile[32][33];
    int r0 = blockIdx.y * 32, c0 = blockIdx.x * 32;
    int t = threadIdx.x;
    int tr = t >> 5, tc = t & 31;
#pragma unroll
    for (int i = 0; i < 4; ++i) {
        int r = r0 + tr + i * 8, c = c0 + tc;
        float v = 0.f;
        if (c < Cc) v = ldin(src, (size_t)r * Cc + c, fl);
        tile[tr + i * 8][tc] = v;
    }
    __syncthreads();
#pragma unroll
    for (int i = 0; i < 4; ++i) {
        int c = c0 + tr + i * 8, r = r0 + tc;
        dst[(size_t)c * R + r] = f2bf(tile[tc][tr + i * 8]);
    }
}

// ---------------- MFMA GEMM (both operands K-contiguous): C = A[M,K] @ Bt[N,K]^T ----------------
__global__ __launch_bounds__(256) void k_gemm_bt(const u16* __restrict__ A, const u16* __restrict__ Bt,
                                                 int K, int mode,
                                                 u16* o0, u16* o1, u16* o2,
                                                 void* outF, const int* flagp) {
    __shared__ __align__(16) u16 sA[4096];
    __shared__ __align__(16) u16 sB[4096];
    int t = threadIdx.x;
    int lane = t & 63, w = t >> 6;
    int wr = w >> 1, wc = w & 1;
    int m0 = blockIdx.y * 128, n0 = blockIdx.x * 128;

    const u16* gA[2]; const u16* gB[2];
    u16* lA[2]; u16* lB[2];
#pragma unroll
    for (int r = 0; r < 2; ++r) {
        int c = w * 128 + r * 64 + lane;
        int m = c >> 2;
        int ks = (c & 3) ^ ((m >> 1) & 3);
        gA[r] = A + (size_t)(m0 + m) * K + ks * 8;
        gB[r] = Bt + (size_t)(n0 + m) * K + ks * 8;
        lA[r] = sA + (size_t)(w * 128 + r * 64) * 8;
        lB[r] = sB + (size_t)(w * 128 + r * 64) * 8;
    }
    int q = lane >> 4, l15 = lane & 15;
    int offA[4], offB[4];
#pragma unroll
    for (int i = 0; i < 4; ++i) {
        int m = wr * 64 + i * 16 + l15;
        offA[i] = (m * 4 + (q ^ ((m >> 1) & 3))) * 8;
        int n = wc * 64 + i * 16 + l15;
        offB[i] = (n * 4 + (q ^ ((n >> 1) & 3))) * 8;
    }
    f32x4 acc[4][4];
#pragma unroll
    for (int i = 0; i < 4; ++i)
#pragma unroll
        for (int j = 0; j < 4; ++j) acc[i][j] = (f32x4){0.f, 0.f, 0.f, 0.f};

    for (int k0 = 0; k0 < K; k0 += 32) {
        gll16(gA[0] + k0, lA[0]);
        gll16(gA[1] + k0, lA[1]);
        gll16(gB[0] + k0, lB[0]);
        gll16(gB[1] + k0, lB[1]);
        __syncthreads();
        bf16x8 af[4], bfv[4];
#pragma unroll
        for (int i = 0; i < 4; ++i) af[i] = *(const bf16x8*)(sA + offA[i]);
#pragma unroll
        for (int i = 0; i < 4; ++i) bfv[i] = *(const bf16x8*)(sB + offB[i]);
#pragma unroll
        for (int i = 0; i < 4; ++i)
#pragma unroll
            for (int j = 0; j < 4; ++j)
                acc[i][j] = __builtin_amdgcn_mfma_f32_16x16x32_bf16(af[i], bfv[j], acc[i][j], 0, 0, 0);
        __syncthreads();
    }

    int fl = (mode == 1) ? *flagp : 0;
#pragma unroll
    for (int i = 0; i < 4; ++i) {
#pragma unroll
        for (int j = 0; j < 4; ++j) {
            int mrow = m0 + wr * 64 + i * 16 + q * 4;
            int n = n0 + wc * 64 + j * 16 + l15;
#pragma unroll
            for (int r = 0; r < 4; ++r) {
                float v = acc[i][j][r];
                size_t m = (size_t)(mrow + r);
                if (mode == 0) {
                    if (n < DIN) o0[m * DIN + n] = f2bf(v);
                    else if (n < DIN + CONVD) o1[m * CONVD + (n - DIN)] = f2bf(v);
                    else if (n < DPROJ) o2[m * NH + (n - DIN - CONVD)] = f2bf(v);
                } else {
                    stout(outF, m * 1024 + n, fl, v);
                }
            }
        }
    }
}

// ---------------- dt softplus + per-chunk cumsum of dA ----------------
__global__ __launch_bounds__(256) void k_dtcum(const u16* DTraw, const void* dtb, const void* alog,
                                               const int* flagp, float* DT, float* ACS, float* AL) {
    int fl = *flagp;
    int bid = blockIdx.x;                 // (b*16+c)*32+h
    int b = bid >> 9, c = (bid >> 5) & 15, h = bid & 31;
    int t = threadIdx.x;
    size_t bl = (size_t)b * LL + c * CH + t;
    float v = bf2f(DTraw[bl * NH + h]) + ldin(dtb, h, fl);
    float sp = (v > 20.f) ? v : log1pf(__expf(v));
    DT[bl * NH + h] = sp;
    float da = -__expf(ldin(alog, h, fl)) * sp;
    __shared__ float sc[256];
    sc[t] = da;
    __syncthreads();
    for (int off = 1; off < 256; off <<= 1) {
        float add = (t >= off) ? sc[t - off] : 0.f;
        __syncthreads();
        sc[t] += add;
        __syncthreads();
    }
    ACS[(size_t)bid * CH + t] = sc[t];
    if (t == 255) AL[bid] = sc[255];
}

// ---------------- causal depthwise conv (width 4) + silu ----------------
__global__ void k_conv(const u16* XBCr, const void* cw, const void* cb, const int* flagp, u16* XCb) {
    int fl = *flagp;
    int ch = blockIdx.x * 256 + threadIdx.x;   // 0..2303 (grid.x = 9)
    size_t bl = blockIdx.y;                    // 0..8191
    int l = (int)(bl & 4095);
    float acc = ldin(cb, ch, fl);
#pragma unroll
    for (int j = 0; j < 4; ++j) {
        int ls = l + j - 3;
        if (ls >= 0)
            acc += bf2f(XBCr[(bl - l + ls) * CONVD + ch]) * ldin(cw, (size_t)ch * 4 + j, fl);
    }
    acc = acc / (1.f + __expf(-acc));
    XCb[bl * CONVD + ch] = f2bf(acc);
}

// ---------------- scores G[l,s] = C[l].B[s] per (b,c) ----------------
__global__ __launch_bounds__(256) void k_scores(const u16* XCb, u16* G) {
    int z = blockIdx.z;   // b*16+c
    const u16* base = XCb + (size_t)z * CH * CONVD;
    __shared__ float As[16][68];
    __shared__ float Bs[16][68];
    int t = threadIdx.x;
    int tx = t & 15, ty = t >> 4;
    int m0 = blockIdx.y * 64, n0 = blockIdx.x * 64;
    float acc[4][4];
#pragma unroll
    for (int i = 0; i < 4; ++i)
#pragma unroll
        for (int j = 0; j < 4; ++j) acc[i][j] = 0.f;

    for (int k0 = 0; k0 < DS; k0 += 16) {
        for (int i = t; i < 1024; i += 256) {
            int m = i >> 4, k = i & 15;
            As[k][m] = bf2f(base[(size_t)(m0 + m) * CONVD + (DIN + DS) + k0 + k]);
        }
        for (int i = t; i < 1024; i += 256) {
            int n = i >> 4, k = i & 15;
            Bs[k][n] = bf2f(base[(size_t)(n0 + n) * CONVD + DIN + k0 + k]);
        }
        __syncthreads();
#pragma unroll
        for (int k = 0; k < 16; ++k) {
            float4 a4 = *(const float4*)&As[k][ty * 4];
            float4 b4 = *(const float4*)&Bs[k][tx * 4];
            float av[4] = {a4.x, a4.y, a4.z, a4.w};
            float bv[4] = {b4.x, b4.y, b4.z, b4.w};
#pragma unroll
            for (int i = 0; i < 4; ++i)
#pragma unroll
                for (int j = 0; j < 4; ++j) acc[i][j] += av[i] * bv[j];
        }
        __syncthreads();
    }
    size_t gb = (size_t)z * 65536;
#pragma unroll
    for (int i = 0; i < 4; ++i) {
        int m = m0 + ty * 4 + i;
#pragma unroll
        for (int j = 0; j < 4; ++j) {
            int n = n0 + tx * 4 + j;
            G[gb + (size_t)m * CH + n] = f2bf(acc[i][j]);
        }
    }
}

// ---------------- per-chunk states via MFMA: STt[p][n] = sum_l X[l,p]*wl[l] * B[l,n] ----------------
__global__ __launch_bounds__(256) void k_states(const u16* XCb, const float* DT, const float* ACS,
                                                const float* AL, u16* STt) {
    int bid = blockIdx.x;            // (b*16+c)*32+h
    int b = bid >> 9, c = (bid >> 5) & 15, h = bid & 31;
    int t = threadIdx.x;
    size_t bL = (size_t)b * LL + c * CH;
    __shared__ float wl[256];
    __shared__ __align__(16) u16 Wt[128 * 38];   // B^T: [n][lk]
    __shared__ __align__(16) u16 Pt[64 * 38];    // X^T*wl: [p][lk]
    float al = AL[bid];
    wl[t] = __expf(al - ACS[(size_t)bid * CH + t]) * DT[(bL + t) * NH + h];
    __syncthreads();

    int lane = t & 63, w = t >> 6;
    int q = lane >> 4, l15 = lane & 15;
    f32x4 acc[8];
#pragma unroll
    for (int j = 0; j < 8; ++j) acc[j] = (f32x4){0.f, 0.f, 0.f, 0.f};

    for (int kt = 0; kt < 8; ++kt) {
        int l0 = kt * 32;
        if (kt) __syncthreads();
#pragma unroll
        for (int e = 0; e < 16; ++e) {
            int i = e * 256 + t;
            int n = i & 127, lk = i >> 7;
            Wt[n * 38 + lk] = XCb[(bL + l0 + lk) * CONVD + DIN + n];
        }
#pragma unroll
        for (int e = 0; e < 8; ++e) {
            int i = e * 256 + t;
            int p = i & 63, lk = i >> 6;
            float v = bf2f(XCb[(bL + l0 + lk) * CONVD + h * HD + p]) * wl[l0 + lk];
            Pt[p * 38 + lk] = f2bf(v);
        }
        __syncthreads();
        bf16x8 af = *(const bf16x8*)&Pt[(w * 16 + l15) * 38 + q * 8];
#pragma unroll
        for (int j = 0; j < 8; ++j) {
            bf16x8 bv = *(const bf16x8*)&Wt[(j * 16 + l15) * 38 + q * 8];
            acc[j] = __builtin_amdgcn_mfma_f32_16x16x32_bf16(af, bv, acc[j], 0, 0, 0);
        }
    }
    size_t sbase = (size_t)bid * 8192;
#pragma unroll
    for (int j = 0; j < 8; ++j)
#pragma unroll
        for (int r = 0; r < 4; ++r)
            STt[sbase + (size_t)(w * 16 + q * 4 + r) * 128 + j * 16 + l15] = f2bf(acc[j][r]);
}

// ---------------- inter-chunk scan (in place; f32 carry; layout-agnostic) ----------------
__global__ __launch_bounds__(256) void k_scan(const float* AL, u16* ST) {
    int bid = blockIdx.x;  // b*32+h
    int b = bid >> 5, h = bid & 31;
    int t = threadIdx.x;
    float Pv[32];
#pragma unroll
    for (int k = 0; k < 32; ++k) Pv[k] = 0.f;
    for (int c = 0; c < NC; ++c) {
        int bch = (b * NC + c) * NH + h;
        float ga = __expf(AL[bch]);
        size_t base = (size_t)bch * 8192;
#pragma unroll
        for (int k = 0; k < 32; ++k) {
            size_t idx = base + (size_t)k * 256 + t;
            float s = bf2f(ST[idx]);
            ST[idx] = f2bf(Pv[k]);
            Pv[k] = ga * Pv[k] + s;
        }
    }
}

// ---------------- Y = Y_off + Y_diag via MFMA, 64 l-rows per block ----------------
__global__ __launch_bounds__(256) void k_ydiag(const u16* XCb, const float* DT, const float* ACS,
                                               const u16* G, const u16* STt, u16* Yb) {
    int bid = blockIdx.x >> 2;       // (b*16+c)*32+h
    int lt = blockIdx.x & 3;
    int b = bid >> 9, c = (bid >> 5) & 15, h = bid & 31;
    int t = threadIdx.x;
    int l0b = lt * 64;
    size_t bL = (size_t)b * LL + c * CH;
    size_t gbase = (size_t)(b * NC + c) * 65536;
    size_t pbase = (size_t)bid * 8192;
    __shared__ float acs_s[256];
    __shared__ float dts_s[256];
    __shared__ float rowf[64], ea[64];
    __shared__ float colf[192];
    __shared__ __align__(16) u16 Wt[64 * 38];
    __shared__ __align__(16) u16 Pt[64 * 38];

    acs_s[t] = ACS[(size_t)bid * CH + t];
    dts_s[t] = DT[(bL + t) * NH + h];
    __syncthreads();
    float aref = acs_s[l0b];
    if (t < 64) {
        rowf[t] = __expf(acs_s[l0b + t] - aref);
        ea[t]   = __expf(acs_s[l0b + t]);
    } else if (t - 64 < l0b) {
        int s = t - 64;
        colf[s] = __expf(aref - acs_s[s]);
    }
    __syncthreads();

    int lane = t & 63, w = t >> 6;
    int q = lane >> 4, l15 = lane & 15;
    f32x4 acc[4];
#pragma unroll
    for (int j = 0; j < 4; ++j) acc[j] = (f32x4){0.f, 0.f, 0.f, 0.f};

    int nd = lt * 2 + 2;             // diag K-tiles (32 wide)
    for (int kt = 0; kt < nd + 4; ++kt) {
        if (kt) __syncthreads();
        if (kt < nd) {
            int s0 = kt * 32;
            if (s0 < l0b) {
                // factored decay: W = G * rowf[l] * colf[s]
#pragma unroll
                for (int e = 0; e < 8; ++e) {
                    int i = e * 256 + t;
                    int sk = i & 31, lr = i >> 5;
                    int s = s0 + sk;
                    float g = bf2f(G[gbase + (size_t)(l0b + lr) * 256 + s]);
                    Wt[lr * 38 + sk] = f2bf(g * rowf[lr] * colf[s]);
                }
            } else {
                // diagonal region: direct masked exp
#pragma unroll
                for (int e = 0; e < 8; ++e) {
                    int i = e * 256 + t;
                    int sk = i & 31, lr = i >> 5;
                    int s = s0 + sk, l = l0b + lr;
                    float wv = 0.f;
                    if (l >= s)
                        wv = bf2f(G[gbase + (size_t)l * 256 + s]) * __expf(acs_s[l] - acs_s[s]);
                    Wt[lr * 38 + sk] = f2bf(wv);
                }
            }
            // B: Pt[p][sk] = X[s,p]*dt[s]
#pragma unroll
            for (int e = 0; e < 8; ++e) {
                int i = e * 256 + t;
                int p = i & 63, sk = i >> 6;
                int s = s0 + sk;
                float v = bf2f(XCb[(bL + s) * CONVD + h * HD + p]) * dts_s[s];
                Pt[p * 38 + sk] = f2bf(v);
            }
        } else {
            int n0 = (kt - nd) * 32;
            // A: Wt[lr][nk] = C[l,n]*exp(acs[l])
#pragma unroll
            for (int e = 0; e < 8; ++e) {
                int i = e * 256 + t;
                int nk = i & 31, lr = i >> 5;
                float v = bf2f(XCb[(bL + l0b + lr) * CONVD + DIN + DS + n0 + nk]) * ea[lr];
                Wt[lr * 38 + nk] = f2bf(v);
            }
            // B: Pt[p][nk] = STt[p][n0+nk]  (direct copy)
#pragma unroll
            for (int e = 0; e < 8; ++e) {
                int i = e * 256 + t;
                int nk = i & 31, pr = i >> 5;
                Pt[pr * 38 + nk] = STt[pbase + (size_t)pr * 128 + n0 + nk];
            }
        }
        __syncthreads();
        bf16x8 af = *(const bf16x8*)&Wt[(w * 16 + l15) * 38 + q * 8];
#pragma unroll
        for (int j = 0; j < 4; ++j) {
            bf16x8 bv = *(const bf16x8*)&Pt[(j * 16 + l15) * 38 + q * 8];
            acc[j] = __builtin_amdgcn_mfma_f32_16x16x32_bf16(af, bv, acc[j], 0, 0, 0);
        }
    }
#pragma unroll
    for (int j = 0; j < 4; ++j)
#pragma unroll
        for (int r = 0; r < 4; ++r)
            Yb[(bL + l0b + w * 16 + q * 4 + r) * (size_t)DIN + h * HD + j * 16 + l15] =
                f2bf(acc[j][r]);
}

// ---------------- layernorm * silu(z), in place on Yb ----------------
__global__ __launch_bounds__(256) void k_norm(u16* Yb, const u16* Zb, const void* nw, const int* flagp) {
    int fl = *flagp;
    size_t row = blockIdx.x;
    int t = threadIdx.x;
    size_t base = row * (size_t)DIN;
    float v[8];
#pragma unroll
    for (int k = 0; k < 8; ++k) v[k] = bf2f(Yb[base + k * 256 + t]);
    float s = 0.f;
#pragma unroll
    for (int k = 0; k < 8; ++k) s += v[k];
#pragma unroll
    for (int off = 32; off > 0; off >>= 1) s += __shfl_down(s, off);
    __shared__ float red[4];
    int wid = t >> 6, lid = t & 63;
    if (lid == 0) red[wid] = s;
    __syncthreads();
    float mu = (red[0] + red[1] + red[2] + red[3]) * (1.f / 2048.f);
    float d = 0.f;
#pragma unroll
    for (int k = 0; k < 8; ++k) { float e = v[k] - mu; d += e * e; }
#pragma unroll
    for (int off = 32; off > 0; off >>= 1) d += __shfl_down(d, off);
    __syncthreads();
    if (lid == 0) red[wid] = d;
    __syncthreads();
    float var = (red[0] + red[1] + red[2] + red[3]) * (1.f / 2048.f);
    float rs = rsqrtf(var + 1e-5f);
#pragma unroll
    for (int k = 0; k < 8; ++k) {
        int dcol = k * 256 + t;
        float z = bf2f(Zb[row * DIN + dcol]);
        float sz = z / (1.f + __expf(-z));
        Yb[base + dcol] = f2bf((v[k] - mu) * rs * ldin(nw, dcol, fl) * sz);
    }
}

extern "C" void kernel_launch(void* const* d_in, const int* in_sizes, int n_in,
                              void* d_out, int out_size, void* d_ws, size_t ws_size,
                              hipStream_t stream) {
    const void* u    = d_in[0];
    const void* Win  = d_in[1];
    const void* cw   = d_in[2];
    const void* cb   = d_in[3];
    const void* dtb  = d_in[4];
    const void* alog = d_in[5];
    const void* nw   = d_in[6];
    const void* Wout = d_in[7];

    char* base = (char*)d_ws;
    int*  flag  = (int*)base;
    u16*  Zb    = (u16*)(base + 256);
    u16*  XBCr  = (u16*)(base + 33554688);
    u16*  XCb   = (u16*)(base + 71303424);
    u16*  ST    = (u16*)(base + 109052160);
    u16*  G     = (u16*)(base + 125829376);
    float* DT   = (float*)(base + 130023680);
    float* ACS  = (float*)(base + 131072256);
    float* AL   = (float*)(base + 132120832);
    u16*  DTraw = (u16*)(base + 132124928);
    u16*  Yb    = XBCr;
    u16*  Ub    = (u16*)(base + 71303424);
    u16*  WinT  = (u16*)(base + 88080640);
    u16*  WoutT = (u16*)(base + 109052160);

    k_detect<<<1, 256, 0, stream>>>(u, flag);
    k_cast<<<8192, 256, 0, stream>>>(u, Ub, flag, 2097152);
    k_transpose<<<dim3(140, 32), 256, 0, stream>>>(Win, WinT, 1024, 4384, flag);
    k_gemm_bt<<<dim3(35, 64), 256, 0, stream>>>(Ub, WinT, 1024, 0, Zb, XBCr, DTraw, nullptr, flag);
    k_dtcum<<<1024, 256, 0, stream>>>(DTraw, dtb, alog, flag, DT, ACS, AL);
    k_conv<<<dim3(9, 8192), 256, 0, stream>>>(XBCr, cw, cb, flag, XCb);
    k_scores<<<dim3(4, 4, 32), 256, 0, stream>>>(XCb, G);
    k_states<<<1024, 256, 0, stream>>>(XCb, DT, ACS, AL, ST);
    k_scan<<<64, 256, 0, stream>>>(AL, ST);
    k_ydiag<<<4096, 256, 0, stream>>>(XCb, DT, ACS, G, ST, Yb);
    k_transpose<<<dim3(32, 64), 256, 0, stream>>>(Wout, WoutT, 2048, 1024, flag);
    k_norm<<<8192, 256, 0, stream>>>(Yb, Zb, nw, flag);
    k_gemm_bt<<<dim3(8, 64), 256, 0, stream>>>(Yb, WoutT, 2048, 1, nullptr, nullptr, nullptr, d_out, flag);
}